// Round 5
// baseline (101.349 us; speedup 1.0000x reference)
//
#include <hip/hip_runtime.h>

typedef __attribute__((ext_vector_type(8))) short bf16x8;
typedef __attribute__((ext_vector_type(4))) float f32x4;

#define D_MODEL 512
#define SEQ 2048
#define NHEAD 8
#define WIN 128

__device__ inline unsigned short f2bf(float f) {
    unsigned u = __float_as_uint(f);
    unsigned r = (u + 0x7fffu + ((u >> 16) & 1u)) >> 16;   // RNE
    return (unsigned short)r;
}

__device__ inline void async_load16(const void* g, void* l) {
    __builtin_amdgcn_global_load_lds((const __attribute__((address_space(1))) void*)g,
                                     (__attribute__((address_space(3))) void*)l, 16, 0, 0);
}

// ---------------- fused prep: bf16(x) + transposed bf16 weights ----------------
__global__ __launch_bounds__(256) void prep(const float* __restrict__ x,
                                            const float* __restrict__ Wq,
                                            const float* __restrict__ Wk,
                                            const float* __restrict__ Wv,
                                            const float* __restrict__ Wo,
                                            unsigned short* __restrict__ xc,
                                            unsigned short* __restrict__ Wt) {
    __shared__ float tile[32 * 33];
    const int t = threadIdx.x;
    if (blockIdx.x < 2048) {
        int i = blockIdx.x * 256 + t;
        float4 v = ((const float4*)x)[i];
        ushort4 o;
        o.x = f2bf(v.x); o.y = f2bf(v.y); o.z = f2bf(v.z); o.w = f2bf(v.w);
        ((ushort4*)xc)[i] = o;
        return;
    }
    int idx = blockIdx.x - 2048;             // 1024 blocks: 4 mats x 16 x 16 tiles
    const int mat = idx >> 8;
    const int rem = idx & 255;
    const int ti = rem & 15, tj = rem >> 4;  // k-tile, n-tile
    const float* W = mat == 0 ? Wq : mat == 1 ? Wk : mat == 2 ? Wv : Wo;
    {
        int c = t & 31, r4 = (t >> 5) * 4;
        #pragma unroll
        for (int e = 0; e < 4; e++)
            tile[(r4 + e) * 33 + c] = W[(size_t)(ti * 32 + r4 + e) * 512 + tj * 32 + c];
    }
    __syncthreads();
    {
        int rr = t & 31, c4 = (t >> 5) * 4;
        #pragma unroll
        for (int e = 0; e < 4; e++)
            Wt[(size_t)mat * 262144 + (size_t)(tj * 32 + c4 + e) * 512 + ti * 32 + rr] =
                f2bf(tile[rr * 33 + c4 + e]);
    }
}

// ---------------- 128x128-tile bf16 MFMA GEMM, BK=64, XOR-swizzled LDS ---------
// 4 waves in 2x2; wave (wr,wc) owns a 64x64 quadrant, 4x4 accs of 16x16.
// LDS rows are 8 chunks of 16B; physical chunk = logical ^ (row&7), applied on
// the GLOBAL source side so global_load_lds's lane-contiguous dest works.
// Frag rows all satisfy row&7 == lm&7, so one swizzled koff serves all frags.
__global__ __launch_bounds__(256) void gemm128(const unsigned short* __restrict__ A,
                                               const unsigned short* __restrict__ Bt,
                                               unsigned short* __restrict__ C, int Nstride) {
    __shared__ unsigned short As[128 * 64];
    __shared__ unsigned short Bs[128 * 64];
    const int t = threadIdx.x;
    const int w = t >> 6, l = t & 63;
    const int lm = l & 15;
    const int mBase = blockIdx.x * 128;
    const int nBase = blockIdx.y * 128;
    const int wr = (w >> 1) * 64, wc = (w & 1) * 64;

    // staging: 128 rows x 8 chunks = 1024 slots per tensor, 4 slots/thread
    const unsigned short* aptr[4];
    const unsigned short* bptr[4];
    #pragma unroll
    for (int n = 0; n < 4; n++) {
        int s = t + n * 256;
        int r = s >> 3, lc = (s & 7) ^ (r & 7);
        aptr[n] = A  + (size_t)(mBase + r) * 512 + lc * 8;
        bptr[n] = Bt + (size_t)(nBase + r) * 512 + lc * 8;
    }

    f32x4 acc[4][4];
    #pragma unroll
    for (int i = 0; i < 4; i++)
        #pragma unroll
        for (int j = 0; j < 4; j++) acc[i][j] = (f32x4){0.f, 0.f, 0.f, 0.f};

    for (int k0 = 0; k0 < 512; k0 += 64) {
        #pragma unroll
        for (int n = 0; n < 4; n++) {
            async_load16(aptr[n] + k0, &As[(t + n * 256) * 8]);
            async_load16(bptr[n] + k0, &Bs[(t + n * 256) * 8]);
        }
        __syncthreads();
        #pragma unroll
        for (int ks = 0; ks < 2; ks++) {
            const int koff = (((ks * 4 + (l >> 4)) ^ (lm & 7)) * 8);
            bf16x8 af[4], bfr[4];
            #pragma unroll
            for (int i = 0; i < 4; i++)
                af[i] = *(const bf16x8*)&As[(wr + i * 16 + lm) * 64 + koff];
            #pragma unroll
            for (int j = 0; j < 4; j++)
                bfr[j] = *(const bf16x8*)&Bs[(wc + j * 16 + lm) * 64 + koff];
            #pragma unroll
            for (int i = 0; i < 4; i++)
                #pragma unroll
                for (int j = 0; j < 4; j++)
                    acc[i][j] = __builtin_amdgcn_mfma_f32_16x16x32_bf16(af[i], bfr[j], acc[i][j], 0, 0, 0);
        }
        __syncthreads();
    }
    // C/D map: col = lane&15, row = (lane>>4)*4 + reg  [m89-verified]
    const int rRow = (l >> 4) * 4;
    #pragma unroll
    for (int i = 0; i < 4; i++)
        #pragma unroll
        for (int j = 0; j < 4; j++)
            #pragma unroll
            for (int r = 0; r < 4; r++) {
                size_t row = (size_t)(mBase + wr + i * 16 + rRow + r);
                size_t col = (size_t)(nBase + wc + j * 16 + lm);
                C[row * (size_t)Nstride + col] = f2bf(acc[i][j][r]);
            }
}

// ---------------- 64-row-tile bf16 MFMA GEMM (proj), BK=64 ----------------------
template <typename OUT, int NT>
__global__ __launch_bounds__(256) void gemm64(const unsigned short* __restrict__ A,
                                              const unsigned short* __restrict__ Bt,
                                              OUT* __restrict__ C, int Nstride) {
    __shared__ unsigned short As[64 * 64];
    __shared__ unsigned short Bs[NT * 16 * 64];
    const int t = threadIdx.x;
    const int w = t >> 6, l = t & 63;
    const int lm = l & 15;
    const int mBase = blockIdx.x * 64;
    const int nBase = blockIdx.y * (NT * 16);

    const unsigned short* aptr[2];
    #pragma unroll
    for (int n = 0; n < 2; n++) {
        int s = t + n * 256;
        int r = s >> 3, lc = (s & 7) ^ (r & 7);
        aptr[n] = A + (size_t)(mBase + r) * 512 + lc * 8;
    }
    const unsigned short* bptr[NT / 2];
    #pragma unroll
    for (int n = 0; n < NT / 2; n++) {
        int s = t + n * 256;
        int r = s >> 3, lc = (s & 7) ^ (r & 7);
        bptr[n] = Bt + (size_t)(nBase + r) * 512 + lc * 8;
    }

    f32x4 acc[NT];
    #pragma unroll
    for (int j = 0; j < NT; j++) acc[j] = (f32x4){0.f, 0.f, 0.f, 0.f};

    for (int k0 = 0; k0 < 512; k0 += 64) {
        #pragma unroll
        for (int n = 0; n < 2; n++) async_load16(aptr[n] + k0, &As[(t + n * 256) * 8]);
        #pragma unroll
        for (int n = 0; n < NT / 2; n++) async_load16(bptr[n] + k0, &Bs[(t + n * 256) * 8]);
        __syncthreads();
        #pragma unroll
        for (int ks = 0; ks < 2; ks++) {
            const int koff = (((ks * 4 + (l >> 4)) ^ (lm & 7)) * 8);
            bf16x8 af = *(const bf16x8*)&As[(w * 16 + lm) * 64 + koff];
            #pragma unroll
            for (int j = 0; j < NT; j++) {
                bf16x8 bfr = *(const bf16x8*)&Bs[(j * 16 + lm) * 64 + koff];
                acc[j] = __builtin_amdgcn_mfma_f32_16x16x32_bf16(af, bfr, acc[j], 0, 0, 0);
            }
        }
        __syncthreads();
    }
    const int rRow = (l >> 4) * 4;
    #pragma unroll
    for (int j = 0; j < NT; j++)
        #pragma unroll
        for (int r = 0; r < 4; r++) {
            size_t row = (size_t)(mBase + w * 16 + rRow + r);
            size_t col = (size_t)(nBase + j * 16 + lm);
            C[row * (size_t)Nstride + col] = acc[j][r];
        }
}

// ---------------- MFMA sliding-window attention ----------------
__global__ __launch_bounds__(256) void attn_mfma(const unsigned short* __restrict__ QKV,
                                                 unsigned short* __restrict__ AO) {
    __shared__ unsigned short Ks[192 * 64];   // [key j][feat], chunk-swizzled
    __shared__ unsigned short Qs[64 * 64];    // [q][feat], chunk-swizzled
    __shared__ unsigned short Vs[64 * 200];   // [d][key j], chunk-swizzled
    __shared__ unsigned short Pb[4][16 * 40]; // per-wave P bounce

    const int t = threadIdx.x;
    const int w = t >> 6, l = t & 63;
    const int lm = l & 15;
    const int s0 = blockIdx.x * 64;
    const int h = blockIdx.y, b = blockIdx.z;
    const unsigned short* base = QKV + (size_t)b * SEQ * 1536;

    #pragma unroll
    for (int n = 0; n < 6; n++) {
        int i = t + n * 256;
        int j = i >> 3, c8 = i & 7;
        int lc = c8 ^ (j & 7);
        int g = s0 - 127 + j;
        g = g < 0 ? 0 : (g > SEQ - 1 ? SEQ - 1 : g);
        async_load16(base + (size_t)g * 1536 + 512 + h * 64 + lc * 8, &Ks[i * 8]);
    }
    #pragma unroll
    for (int n = 0; n < 2; n++) {
        int i = t + n * 256;
        int j = i >> 3, c8 = i & 7;
        int lc = c8 ^ (j & 7);
        async_load16(base + (size_t)(s0 + j) * 1536 + h * 64 + lc * 8, &Qs[i * 8]);
    }
    for (int i = t; i < 192 * 8; i += 256) {
        int j = i >> 3, c8 = i & 7;
        int g = s0 - 127 + j;
        g = g < 0 ? 0 : (g > SEQ - 1 ? SEQ - 1 : g);
        uint4 vv = *(const uint4*)(base + (size_t)g * 1536 + 1024 + h * 64 + c8 * 8);
        unsigned short e16[8];
        *(uint4*)e16 = vv;
        int chunk = (j >> 3) ^ c8;           // (d>>3)&7 == c8 for d in [8*c8, 8*c8+8)
        int off = chunk * 8 + (j & 7);
        #pragma unroll
        for (int e = 0; e < 8; e++)
            Vs[(c8 * 8 + e) * 200 + off] = e16[e];
    }
    __syncthreads();

    // ---- scores: S[16 q][192 j] via MFMA ----
    f32x4 sc[12];
    #pragma unroll
    for (int kb = 0; kb < 12; kb++) sc[kb] = (f32x4){0.f, 0.f, 0.f, 0.f};
    #pragma unroll
    for (int ks = 0; ks < 2; ks++) {
        const int cq = ks * 4 + (l >> 4);
        bf16x8 aq = *(const bf16x8*)&Qs[(w * 16 + lm) * 64 + ((cq ^ (lm & 7)) * 8)];
        #pragma unroll
        for (int kb = 0; kb < 12; kb++) {
            int row = kb * 16 + lm;
            bf16x8 bk = *(const bf16x8*)&Ks[row * 64 + ((cq ^ (row & 7)) * 8)];
            sc[kb] = __builtin_amdgcn_mfma_f32_16x16x32_bf16(aq, bk, sc[kb], 0, 0, 0);
        }
    }

    // ---- mask + scale + in-register softmax ----
    const int qr0 = (l >> 4) * 4;
    const int jlo_g = 127 - s0;
    float mrow[4] = {-1e30f, -1e30f, -1e30f, -1e30f};
    #pragma unroll
    for (int kb = 0; kb < 12; kb++) {
        int j = kb * 16 + lm;
        #pragma unroll
        for (int r = 0; r < 4; r++) {
            int qi = w * 16 + qr0 + r;
            bool valid = (j >= qi) & (j <= qi + 127) & (j >= jlo_g);
            float v = valid ? sc[kb][r] * 0.125f : -1e30f;
            sc[kb][r] = v;
            mrow[r] = fmaxf(mrow[r], v);
        }
    }
    #pragma unroll
    for (int r = 0; r < 4; r++) {
        mrow[r] = fmaxf(mrow[r], __shfl_xor(mrow[r], 1));
        mrow[r] = fmaxf(mrow[r], __shfl_xor(mrow[r], 2));
        mrow[r] = fmaxf(mrow[r], __shfl_xor(mrow[r], 4));
        mrow[r] = fmaxf(mrow[r], __shfl_xor(mrow[r], 8));
    }
    float srow[4] = {0.f, 0.f, 0.f, 0.f};
    #pragma unroll
    for (int kb = 0; kb < 12; kb++)
        #pragma unroll
        for (int r = 0; r < 4; r++) {
            float p = __expf(sc[kb][r] - mrow[r]);
            sc[kb][r] = p;
            srow[r] += p;
        }
    #pragma unroll
    for (int r = 0; r < 4; r++) {
        srow[r] += __shfl_xor(srow[r], 1);
        srow[r] += __shfl_xor(srow[r], 2);
        srow[r] += __shfl_xor(srow[r], 4);
        srow[r] += __shfl_xor(srow[r], 8);
        srow[r] = 1.f / srow[r];
    }

    // ---- PV: O[16 q][64 d]; P -> per-wave LDS bounce -> A-frag ----
    f32x4 ov[4];
    #pragma unroll
    for (int nb = 0; nb < 4; nb++) ov[nb] = (f32x4){0.f, 0.f, 0.f, 0.f};
    unsigned short* pb = &Pb[w][0];
    #pragma unroll
    for (int c = 0; c < 6; c++) {
        #pragma unroll
        for (int kk = 0; kk < 2; kk++)
            #pragma unroll
            for (int r = 0; r < 4; r++)
                pb[(qr0 + r) * 40 + kk * 16 + lm] = f2bf(sc[2 * c + kk][r]);
        bf16x8 ap = *(const bf16x8*)&pb[lm * 40 + (l >> 4) * 8];
        #pragma unroll
        for (int nb = 0; nb < 4; nb++) {
            int d = nb * 16 + lm;
            int cj = c * 4 + (l >> 4);                  // logical 16B chunk of j
            int off = ((cj ^ ((d >> 3) & 7)) * 8);
            bf16x8 bv = *(const bf16x8*)&Vs[d * 200 + off];
            ov[nb] = __builtin_amdgcn_mfma_f32_16x16x32_bf16(ap, bv, ov[nb], 0, 0, 0);
        }
    }

    // ---- epilogue ----
    #pragma unroll
    for (int nb = 0; nb < 4; nb++)
        #pragma unroll
        for (int r = 0; r < 4; r++) {
            size_t row = (size_t)(b * SEQ + s0 + w * 16 + qr0 + r);
            AO[row * 512 + h * 64 + nb * 16 + lm] = f2bf(ov[nb][r] * srow[r]);
        }
}

extern "C" void kernel_launch(void* const* d_in, const int* in_sizes, int n_in,
                              void* d_out, int out_size, void* d_ws, size_t ws_size,
                              hipStream_t stream) {
    const float* x  = (const float*)d_in[0];
    const float* Wq = (const float*)d_in[1];
    const float* Wk = (const float*)d_in[2];
    const float* Wv = (const float*)d_in[3];
    const float* Wo = (const float*)d_in[4];
    float* out = (float*)d_out;

    char* ws = (char*)d_ws;
    unsigned short* xc  = (unsigned short*)ws;                          // 4 MiB
    unsigned short* Wt  = (unsigned short*)(ws + 4u * 1024 * 1024);     // 2 MiB
    unsigned short* QKV = (unsigned short*)(ws + 6u * 1024 * 1024);     // 12 MiB
    unsigned short* AO  = (unsigned short*)(ws + 18u * 1024 * 1024);    // 4 MiB

    prep<<<3072, 256, 0, stream>>>(x, Wq, Wk, Wv, Wo, xc, Wt);
    // fused QKV projection: 128x128 tiles, BK=64 -> 384 blocks, 96 MB staged
    gemm128<<<dim3(32, 12), 256, 0, stream>>>(xc, Wt, QKV, 1536);
    attn_mfma<<<dim3(32, 8, 2), 256, 0, stream>>>(QKV, AO);
    // output projection: 64x64 tiles, BK=64 -> 512 blocks (2/CU)
    gemm64<float, 4><<<dim3(64, 8), 256, 0, stream>>>(AO, Wt + 3 * 262144, out, 512);
}

// Round 6
// 100.330 us; speedup vs baseline: 1.0102x; 1.0102x over previous
//
#include <hip/hip_runtime.h>

typedef __attribute__((ext_vector_type(8))) short bf16x8;
typedef __attribute__((ext_vector_type(4))) float f32x4;

#define D_MODEL 512
#define SEQ 2048
#define NHEAD 8
#define WIN 128

__device__ inline unsigned short f2bf(float f) {
    unsigned u = __float_as_uint(f);
    unsigned r = (u + 0x7fffu + ((u >> 16) & 1u)) >> 16;   // RNE
    return (unsigned short)r;
}

__device__ inline void async_load16(const void* g, void* l) {
    __builtin_amdgcn_global_load_lds((const __attribute__((address_space(1))) void*)g,
                                     (__attribute__((address_space(3))) void*)l, 16, 0, 0);
}

// ---------------- fused prep: bf16(x) + transposed bf16 weights ----------------
__global__ __launch_bounds__(256) void prep(const float* __restrict__ x,
                                            const float* __restrict__ Wq,
                                            const float* __restrict__ Wk,
                                            const float* __restrict__ Wv,
                                            const float* __restrict__ Wo,
                                            unsigned short* __restrict__ xc,
                                            unsigned short* __restrict__ Wt) {
    __shared__ float tile[32 * 33];
    const int t = threadIdx.x;
    if (blockIdx.x < 2048) {
        int i = blockIdx.x * 256 + t;
        float4 v = ((const float4*)x)[i];
        ushort4 o;
        o.x = f2bf(v.x); o.y = f2bf(v.y); o.z = f2bf(v.z); o.w = f2bf(v.w);
        ((ushort4*)xc)[i] = o;
        return;
    }
    int idx = blockIdx.x - 2048;             // 1024 blocks: 4 mats x 16 x 16 tiles
    const int mat = idx >> 8;
    const int rem = idx & 255;
    const int ti = rem & 15, tj = rem >> 4;  // k-tile, n-tile
    const float* W = mat == 0 ? Wq : mat == 1 ? Wk : mat == 2 ? Wv : Wo;
    {
        int c = t & 31, r4 = (t >> 5) * 4;
        #pragma unroll
        for (int e = 0; e < 4; e++)
            tile[(r4 + e) * 33 + c] = W[(size_t)(ti * 32 + r4 + e) * 512 + tj * 32 + c];
    }
    __syncthreads();
    {
        int rr = t & 31, c4 = (t >> 5) * 4;
        #pragma unroll
        for (int e = 0; e < 4; e++)
            Wt[(size_t)mat * 262144 + (size_t)(tj * 32 + c4 + e) * 512 + ti * 32 + rr] =
                f2bf(tile[rr * 33 + c4 + e]);
    }
}

// ---------------- 64-row-tile bf16 MFMA GEMM, BK=64, XOR-swizzled LDS ----------
// Tile 64 x (NT*16). 4 waves; wave w owns rows [w*16, w*16+16). K = 512.
// LDS tile rows are 8 chunks of 16B; physical chunk = logical ^ (row&7), applied
// on the GLOBAL source side so global_load_lds's lane-contiguous dest works.
// Frag reads then hit 2-way banks (free) instead of 8/16-way.
// NOTE (R5 post-mortem): 128x128 tiles (384 blocks, 1.5/CU) REGRESSED vs this
// 64-row config (768 blocks, 3/CU) — block-count granularity dominates staged
// L2 bytes at this problem scale. Keep >=2 uniform blocks/CU.
__device__ inline void storeC(float* C, size_t i, float v) { C[i] = v; }
__device__ inline void storeC(unsigned short* C, size_t i, float v) { C[i] = f2bf(v); }

template <typename OUT, int NT>
__global__ __launch_bounds__(256) void gemm64(const unsigned short* __restrict__ A,
                                              const unsigned short* __restrict__ Bt,
                                              OUT* __restrict__ C, int Nstride) {
    __shared__ unsigned short As[64 * 64];
    __shared__ unsigned short Bs[NT * 16 * 64];
    const int t = threadIdx.x;
    const int w = t >> 6, l = t & 63;
    const int lm = l & 15;
    const int mBase = blockIdx.x * 64;
    const int nBase = blockIdx.y * (NT * 16);

    // staging slot s -> row s>>3, physical chunk s&7, logical chunk (s&7)^(row&7)
    const unsigned short* aptr[2];
    #pragma unroll
    for (int n = 0; n < 2; n++) {
        int s = t + n * 256;
        int r = s >> 3, lc = (s & 7) ^ (r & 7);
        aptr[n] = A + (size_t)(mBase + r) * 512 + lc * 8;
    }
    const unsigned short* bptr[NT / 2];
    #pragma unroll
    for (int n = 0; n < NT / 2; n++) {
        int s = t + n * 256;
        int r = s >> 3, lc = (s & 7) ^ (r & 7);
        bptr[n] = Bt + (size_t)(nBase + r) * 512 + lc * 8;
    }

    f32x4 acc[NT];
    #pragma unroll
    for (int j = 0; j < NT; j++) acc[j] = (f32x4){0.f, 0.f, 0.f, 0.f};

    for (int k0 = 0; k0 < 512; k0 += 64) {
        #pragma unroll
        for (int n = 0; n < 2; n++) async_load16(aptr[n] + k0, &As[(t + n * 256) * 8]);
        #pragma unroll
        for (int n = 0; n < NT / 2; n++) async_load16(bptr[n] + k0, &Bs[(t + n * 256) * 8]);
        __syncthreads();
        #pragma unroll
        for (int ks = 0; ks < 2; ks++) {
            const int koff = (((ks * 4 + (l >> 4)) ^ (lm & 7)) * 8);
            bf16x8 af = *(const bf16x8*)&As[(w * 16 + lm) * 64 + koff];
            #pragma unroll
            for (int j = 0; j < NT; j++) {
                bf16x8 bfr = *(const bf16x8*)&Bs[(j * 16 + lm) * 64 + koff];
                acc[j] = __builtin_amdgcn_mfma_f32_16x16x32_bf16(af, bfr, acc[j], 0, 0, 0);
            }
        }
        __syncthreads();
    }
    // C/D map: col = lane&15, row = (lane>>4)*4 + reg  [m89-verified]
    const int rRow = (l >> 4) * 4;
    #pragma unroll
    for (int j = 0; j < NT; j++)
        #pragma unroll
        for (int r = 0; r < 4; r++) {
            size_t row = (size_t)(mBase + w * 16 + rRow + r);
            size_t col = (size_t)(nBase + j * 16 + lm);
            storeC(C, row * (size_t)Nstride + col, acc[j][r]);
        }
}

// ---------------- MFMA sliding-window attention ----------------
// Block: 64 queries x 1 head x 1 batch; wave w -> queries [w*16, w*16+16).
// Keys j=0..191 <-> g = s0-127+j. Valid: j in [max(qi,127-s0), qi+127].
// K/Q staged async with the same XOR chunk swizzle (unpadded stride-64 rows).
__global__ __launch_bounds__(256) void attn_mfma(const unsigned short* __restrict__ QKV,
                                                 unsigned short* __restrict__ AO) {
    __shared__ unsigned short Ks[192 * 64];   // [key j][feat], chunk-swizzled
    __shared__ unsigned short Qs[64 * 64];    // [q][feat], chunk-swizzled
    __shared__ unsigned short Vs[64 * 200];   // [d][key j], chunk-swizzled
    __shared__ unsigned short Pb[4][16 * 40]; // per-wave P bounce

    const int t = threadIdx.x;
    const int w = t >> 6, l = t & 63;
    const int lm = l & 15;
    const int s0 = blockIdx.x * 64;
    const int h = blockIdx.y, b = blockIdx.z;
    const unsigned short* base = QKV + (size_t)b * SEQ * 1536;

    // async-stage K: 192 rows x 8 chunks = 1536 slots (6/thread)
    #pragma unroll
    for (int n = 0; n < 6; n++) {
        int i = t + n * 256;
        int j = i >> 3, c8 = i & 7;
        int lc = c8 ^ (j & 7);
        int g = s0 - 127 + j;
        g = g < 0 ? 0 : (g > SEQ - 1 ? SEQ - 1 : g);
        async_load16(base + (size_t)g * 1536 + 512 + h * 64 + lc * 8, &Ks[i * 8]);
    }
    // async-stage Q: 64 rows x 8 chunks = 512 slots (2/thread)
    #pragma unroll
    for (int n = 0; n < 2; n++) {
        int i = t + n * 256;
        int j = i >> 3, c8 = i & 7;
        int lc = c8 ^ (j & 7);
        async_load16(base + (size_t)(s0 + j) * 1536 + h * 64 + lc * 8, &Qs[i * 8]);
    }
    // stage V transposed: global row j (coalesced 16B) -> Vs[d][j] scalar writes.
    for (int i = t; i < 192 * 8; i += 256) {
        int j = i >> 3, c8 = i & 7;
        int g = s0 - 127 + j;
        g = g < 0 ? 0 : (g > SEQ - 1 ? SEQ - 1 : g);
        uint4 vv = *(const uint4*)(base + (size_t)g * 1536 + 1024 + h * 64 + c8 * 8);
        unsigned short e16[8];
        *(uint4*)e16 = vv;
        int chunk = (j >> 3) ^ c8;           // (d>>3)&7 == c8 for d in [8*c8, 8*c8+8)
        int off = chunk * 8 + (j & 7);
        #pragma unroll
        for (int e = 0; e < 8; e++)
            Vs[(c8 * 8 + e) * 200 + off] = e16[e];
    }
    __syncthreads();

    // ---- scores: S[16 q][192 j] via MFMA ----
    f32x4 sc[12];
    #pragma unroll
    for (int kb = 0; kb < 12; kb++) sc[kb] = (f32x4){0.f, 0.f, 0.f, 0.f};
    #pragma unroll
    for (int ks = 0; ks < 2; ks++) {
        const int cq = ks * 4 + (l >> 4);
        bf16x8 aq = *(const bf16x8*)&Qs[(w * 16 + lm) * 64 + ((cq ^ (lm & 7)) * 8)];
        #pragma unroll
        for (int kb = 0; kb < 12; kb++) {
            int row = kb * 16 + lm;
            bf16x8 bk = *(const bf16x8*)&Ks[row * 64 + ((cq ^ (row & 7)) * 8)];
            sc[kb] = __builtin_amdgcn_mfma_f32_16x16x32_bf16(aq, bk, sc[kb], 0, 0, 0);
        }
    }

    // ---- mask + scale + in-register softmax ----
    const int qr0 = (l >> 4) * 4;
    const int jlo_g = 127 - s0;
    float mrow[4] = {-1e30f, -1e30f, -1e30f, -1e30f};
    #pragma unroll
    for (int kb = 0; kb < 12; kb++) {
        int j = kb * 16 + lm;
        #pragma unroll
        for (int r = 0; r < 4; r++) {
            int qi = w * 16 + qr0 + r;
            bool valid = (j >= qi) & (j <= qi + 127) & (j >= jlo_g);
            float v = valid ? sc[kb][r] * 0.125f : -1e30f;
            sc[kb][r] = v;
            mrow[r] = fmaxf(mrow[r], v);
        }
    }
    #pragma unroll
    for (int r = 0; r < 4; r++) {
        mrow[r] = fmaxf(mrow[r], __shfl_xor(mrow[r], 1));
        mrow[r] = fmaxf(mrow[r], __shfl_xor(mrow[r], 2));
        mrow[r] = fmaxf(mrow[r], __shfl_xor(mrow[r], 4));
        mrow[r] = fmaxf(mrow[r], __shfl_xor(mrow[r], 8));
    }
    float srow[4] = {0.f, 0.f, 0.f, 0.f};
    #pragma unroll
    for (int kb = 0; kb < 12; kb++)
        #pragma unroll
        for (int r = 0; r < 4; r++) {
            float p = __expf(sc[kb][r] - mrow[r]);
            sc[kb][r] = p;
            srow[r] += p;
        }
    #pragma unroll
    for (int r = 0; r < 4; r++) {
        srow[r] += __shfl_xor(srow[r], 1);
        srow[r] += __shfl_xor(srow[r], 2);
        srow[r] += __shfl_xor(srow[r], 4);
        srow[r] += __shfl_xor(srow[r], 8);
        srow[r] = 1.f / srow[r];
    }

    // ---- PV: O[16 q][64 d]; P -> per-wave LDS bounce -> A-frag ----
    f32x4 ov[4];
    #pragma unroll
    for (int nb = 0; nb < 4; nb++) ov[nb] = (f32x4){0.f, 0.f, 0.f, 0.f};
    unsigned short* pb = &Pb[w][0];
    #pragma unroll
    for (int c = 0; c < 6; c++) {
        #pragma unroll
        for (int kk = 0; kk < 2; kk++)
            #pragma unroll
            for (int r = 0; r < 4; r++)
                pb[(qr0 + r) * 40 + kk * 16 + lm] = f2bf(sc[2 * c + kk][r]);
        bf16x8 ap = *(const bf16x8*)&pb[lm * 40 + (l >> 4) * 8];
        #pragma unroll
        for (int nb = 0; nb < 4; nb++) {
            int d = nb * 16 + lm;
            int cj = c * 4 + (l >> 4);                  // logical 16B chunk of j
            int off = ((cj ^ ((d >> 3) & 7)) * 8);
            bf16x8 bv = *(const bf16x8*)&Vs[d * 200 + off];
            ov[nb] = __builtin_amdgcn_mfma_f32_16x16x32_bf16(ap, bv, ov[nb], 0, 0, 0);
        }
    }

    // ---- epilogue ----
    #pragma unroll
    for (int nb = 0; nb < 4; nb++)
        #pragma unroll
        for (int r = 0; r < 4; r++) {
            size_t row = (size_t)(b * SEQ + s0 + w * 16 + qr0 + r);
            AO[row * 512 + h * 64 + nb * 16 + lm] = f2bf(ov[nb][r] * srow[r]);
        }
}

extern "C" void kernel_launch(void* const* d_in, const int* in_sizes, int n_in,
                              void* d_out, int out_size, void* d_ws, size_t ws_size,
                              hipStream_t stream) {
    const float* x  = (const float*)d_in[0];
    const float* Wq = (const float*)d_in[1];
    const float* Wk = (const float*)d_in[2];
    const float* Wv = (const float*)d_in[3];
    const float* Wo = (const float*)d_in[4];
    float* out = (float*)d_out;

    char* ws = (char*)d_ws;
    unsigned short* xc  = (unsigned short*)ws;                          // 4 MiB
    unsigned short* Wt  = (unsigned short*)(ws + 4u * 1024 * 1024);     // 2 MiB
    unsigned short* QKV = (unsigned short*)(ws + 6u * 1024 * 1024);     // 12 MiB
    unsigned short* AO  = (unsigned short*)(ws + 18u * 1024 * 1024);    // 4 MiB

    prep<<<3072, 256, 0, stream>>>(x, Wq, Wk, Wv, Wo, xc, Wt);
    // fused QKV projection: 64x128 tiles, BK=64 -> 768 blocks (3/CU)
    gemm64<unsigned short, 8><<<dim3(64, 12), 256, 0, stream>>>(xc, Wt, QKV, 1536);
    attn_mfma<<<dim3(32, 8, 2), 256, 0, stream>>>(QKV, AO);
    // output projection: 64x64 tiles, BK=64 -> 512 blocks (2/CU)
    gemm64<float, 4><<<dim3(64, 8), 256, 0, stream>>>(AO, Wt + 3 * 262144, out, 512);
}